// Round 5
// baseline (130.950 us; speedup 1.0000x reference)
//
#include <hip/hip_runtime.h>

// RPN anchor-target assignment. B=8, A=184320, G=64.
// Outputs (flat float32, concatenated): labels[B*A], matched[B*A*4], max_iou[B*A].
// Requires A % 768 == 0 (184320 = 240*768).
//
// Sparse-mask strategy, 3 kernels. Per batch, 4 quantized interval tables
// (u64[128], 5px strips) over the 64 gts give each anchor a conservative
// superset mask of possibly-overlapping gts; exact IEEE IoU runs only on mask
// bits. Skipped pairs have true iou==0 (exact via key/init no-op arguments).
//
// R12 (this round): lane-level load balancing via per-chunk LDS work queue.
//  Diagnosis: masks' per-lane popcounts are iid (random anchor sizes), mean
//  ~10 but wave-max ~30-40 -> the divergent while(m) loop wasted ~2x in
//  masked-off lanes (invisible in VALUBusy). Fix:
//  - Per 128-anchor chunk: threads t and t+128 split anchor (t&127)'s mask
//    into lo/hi 32 bits, wave-scan popcounts (shfl prefix + 1 atomicAdd per
//    wave), push (a_loc<<6)|g u16 items into an 8192-entry LDS queue
//    (capacity = 128*64, provably sufficient; no fallback needed).
//  - Dense consume: 1 item/lane/round, lane-transposed odd-stride indexing
//    (no same-round row-atomic collisions; <=2-way queue-read bank aliasing).
//    Per item: identical IEEE IoU + two exact-key LDS atomicMax:
//      col key (iou, 0xFFFFFFFF-a)   [unchanged vs R11]
//      row key (iou, 63-g)           [max == numpy first-max: higher iou,
//                                     then smaller g; bit-exact replacement
//                                     for the sequential strict-> scan]
//    Queue order is irrelevant: all updates are order-free idempotent max
//    with totally-ordered exact keys. Empty-mask anchors decode from the row
//    init 63 -> (iou=0, g=0), matching numpy argmax of an all-zero row.
//  - R10's lesson kept: exhausted/invalid lanes are exec-masked off (no dummy
//    atomics -> no same-address storm).

constexpr int B = 8;
constexpr int G = 64;
constexpr int BLOCK = 256;
constexpr int APT = 3;                 // anchors per thread
constexpr int ABLK = BLOCK * APT;      // anchors per block = 768
constexpr int CHUNK = 128;             // anchors per queue chunk
constexpr int NCHUNK = ABLK / CHUNK;   // 6
constexpr int QCAP = CHUNK * G;        // 8192 items (hard upper bound)
constexpr int NSTRIP = 128;            // 5px strips
constexpr float STRIP_SCALE = 0.2f;
constexpr float STRIP_W = 5.0f;
constexpr float IMG = 640.0f;
constexpr float FG_IOU = 0.7f;
constexpr float BG_IOU = 0.3f;
constexpr float SLACK = 1.0f;
// col key(iou=0, anchor=0): correct for an all-zero column (numpy argmax = 0).
constexpr unsigned long long KEY_INIT = 0xFFFFFFFFull;
// row key(iou=0, g=0): 63-g = 63. Decodes to maxv=0, maxg=0 (numpy exact).
constexpr unsigned long long ROW_INIT = 63ull;

// ws layout: [256]   u64 gkeys[B*G]      (0xAA poison < 0 as i64 == -inf)
//            [8192]  u64 tabs[B][4][128] (built by build_tables each launch)

// tab0 (xlo): gt.x0 < (s+1)*5 + SLACK   used at s=strip(ax1)  ⊇ gt.x0 < ax1
// tab1 (xhi): gt.x1 > s*5 - SLACK       used at s=strip(ax0)  ⊇ gt.x1 > ax0
// tab2 (ylo): gt.y0 < (s+1)*5 + SLACK   used at s=strip(ay1)  ⊇ gt.y0 < ay1
// tab3 (yhi): gt.y1 > s*5 - SLACK       used at s=strip(ay0)  ⊇ gt.y1 > ay0
__global__ __launch_bounds__(512) void build_tables(
    const float4* __restrict__ gt, unsigned long long* __restrict__ tabs) {
    __shared__ float4 sgt[G];
    const int b = blockIdx.x;
    const int t = threadIdx.x;          // 0..511 = tabIdx*128 + strip
    if (t < G) sgt[t] = gt[b * G + t];
    __syncthreads();
    const int tabIdx = t >> 7;
    const int strip = t & 127;
    const int comp = (tabIdx == 0) ? 0 : (tabIdx == 1) ? 2 : (tabIdx == 2) ? 1 : 3;
    const bool hi = (tabIdx & 1) != 0;
    const float thr = hi ? (strip * STRIP_W - SLACK)
                         : ((strip + 1) * STRIP_W + SLACK);
    unsigned long long m = 0ull;
    for (int g = 0; g < G; ++g) {
        float c = ((const float*)&sgt[g])[comp];
        bool in = hi ? (c > thr) : (c < thr);
        if (in) m |= (1ull << g);
    }
    tabs[(size_t)b * 512 + t] = m;
}

__global__ __launch_bounds__(BLOCK) void assign_main(
    const float4* __restrict__ anchors,   // [B*A] cxcywh
    const float4* __restrict__ gt,        // [B*G] xyxy
    float* __restrict__ L,                // labels out [B*A]
    float4* __restrict__ M,               // matched out [B*A]
    float* __restrict__ V,                // max_iou out [B*A]
    long long* __restrict__ gkeys,        // [B*G] global argmax keys (signed max)
    const unsigned long long* __restrict__ tabs,
    int A, int bpb) {
#pragma clang fp contract(off)
    __shared__ float sgx0[G], sgy0[G], sgx1[G], sgy1[G], sga[G];  // gt SoA
    __shared__ unsigned long long tab[4][NSTRIP];                 // 4 KB
    __shared__ unsigned long long skey[G];                        // col keys
    __shared__ unsigned short queue[QCAP];                        // 16 KB
    __shared__ float sax0[CHUNK], say0[CHUNK], sax1[CHUNK], say1[CHUNK],
                     sarea[CHUNK];                                // anchor SoA
    __shared__ unsigned long long rowkey[CHUNK];                  // row keys
    __shared__ int qcnt[NCHUNK];

    const int b = blockIdx.x / bpb;
    const int t = threadIdx.x;
    const int base = (blockIdx.x % bpb) * ABLK;
    const int lane = t & 63;
    const int tl = t & (CHUNK - 1);    // chunk-local anchor owned by this thread

    if (t < G) {
        float4 gb = gt[b * G + t];
        sgx0[t] = gb.x; sgy0[t] = gb.y; sgx1[t] = gb.z; sgy1[t] = gb.w;
        sga[t] = (gb.z - gb.x) * (gb.w - gb.y);
        skey[t] = KEY_INIT;
    }
    if (t < NCHUNK) qcnt[t] = 0;
    {   // 4 KB table: one ulonglong2 (16B) per thread
        const ulonglong2* src = (const ulonglong2*)(tabs + (size_t)b * 512);
        ((ulonglong2*)&tab[0][0])[t] = src[t];
    }

    // Prefetch this thread's chunk anchors (waves 2,3 duplicate waves 0,1's
    // addresses -> L1 hits). Static indexing via full unroll (no scratch).
    float4 anbuf[NCHUNK];
#pragma unroll
    for (int c = 0; c < NCHUNK; ++c)
        anbuf[c] = anchors[(size_t)b * A + base + c * CHUNK + tl];

    __syncthreads();

#pragma unroll
    for (int c = 0; c < NCHUNK; ++c) {
        // ---- build: masks + queue fill (all 256 threads; t<128 lo bits,
        //      t>=128 hi bits of anchor tl's mask) ----
        const float4 an = anbuf[c];
        const float ax0 = an.x - 0.5f * an.z;
        const float ay0 = an.y - 0.5f * an.w;
        const float ax1 = an.x + 0.5f * an.z;
        const float ay1 = an.y + 0.5f * an.w;
        const float area_a = (ax1 - ax0) * (ay1 - ay0);  // numpy corner-derived

        if (t < CHUNK) {
            sax0[tl] = ax0; say0[tl] = ay0; sax1[tl] = ax1; say1[tl] = ay1;
            sarea[tl] = area_a;
            rowkey[tl] = ROW_INIT;
        }

        int sx0 = (int)(ax0 * STRIP_SCALE); sx0 = sx0 < 0 ? 0 : (sx0 > 127 ? 127 : sx0);
        int sx1 = (int)(ax1 * STRIP_SCALE); sx1 = sx1 < 0 ? 0 : (sx1 > 127 ? 127 : sx1);
        int sy0 = (int)(ay0 * STRIP_SCALE); sy0 = sy0 < 0 ? 0 : (sy0 > 127 ? 127 : sy0);
        int sy1 = (int)(ay1 * STRIP_SCALE); sy1 = sy1 < 0 ? 0 : (sy1 > 127 ? 127 : sy1);
        const unsigned long long mask =
            tab[0][sx1] & tab[1][sx0] & tab[2][sy1] & tab[3][sy0];

        unsigned hm = (t < CHUNK) ? (unsigned)mask : (unsigned)(mask >> 32);
        const int gb2 = (t < CHUNK) ? 0 : 32;
        const int pop = __builtin_popcount(hm);

        // wave inclusive scan of pop -> one atomicAdd per wave (4-way contention)
        int x = pop;
#pragma unroll
        for (int d = 1; d < 64; d <<= 1) {
            int y = __shfl_up(x, d, 64);
            if (lane >= d) x += y;
        }
        int wbase = 0;
        if (lane == 63) wbase = atomicAdd(&qcnt[c], x);
        wbase = __shfl(wbase, 63, 64);
        int p = wbase + x - pop;           // exclusive position

        while (hm) {
            const int g = gb2 + (int)__builtin_ctz(hm);
            hm &= hm - 1;
            queue[p++] = (unsigned short)((tl << 6) | g);
        }
        __syncthreads();

        // ---- consume: dense, 1 item/lane/round, lane-transposed odd stride ----
        const int nq = qcnt[c];
        const int R = (nq + BLOCK - 1) >> 8;
        const int Rp = R | 1;              // odd stride: <=2-way bank aliasing
        const int ibase = t * Rp;

        auto consume = [&](int i) {
            if (i < nq) {
                const int item = (int)queue[i];
                const int al = item >> 6;
                const int g = item & 63;
                const float bx0 = sax0[al], by0 = say0[al];
                const float bx1 = sax1[al], by1 = say1[al];
                const float ba  = sarea[al];
                const float gx0 = sgx0[g], gy0 = sgy0[g];
                const float gx1 = sgx1[g], gy1 = sgy1[g];
                const float ga  = sga[g];
                float lx = fmaxf(bx0, gx0), ly = fmaxf(by0, gy0);
                float rx = fminf(bx1, gx1), ry = fminf(by1, gy1);
                float w = fmaxf(rx - lx, 0.0f), h = fmaxf(ry - ly, 0.0f);
                float inter = w * h;
                float uni = ba + ga - inter;
                float iou = inter / uni;     // IEEE div: bit-exact vs numpy
                const unsigned ag = (unsigned)(base + c * CHUNK + al);
                const unsigned long long hi =
                    (unsigned long long)__float_as_uint(iou) << 32;
                // iou==0 keys can never beat the inits: natural no-ops.
                atomicMax(&skey[g], hi | (unsigned long long)(0xFFFFFFFFu - ag));
                atomicMax(&rowkey[al], hi | (unsigned long long)(63 - g));
            }
        };
        for (int r = 0; r + 1 < Rp; r += 2) {   // 2-way ILP across rounds
            consume(ibase + r);
            consume(ibase + r + 1);
        }
        consume(ibase + Rp - 1);                // Rp is odd: single tail
        __syncthreads();

        // ---- epilogue: per-anchor outputs (t<128; same-thread WAR with next
        //      chunk's build, so no extra barrier needed) ----
        if (t < CHUNK) {
            const unsigned long long key = rowkey[t];
            const float maxv = __uint_as_float((unsigned)(key >> 32));
            const int maxg = 63 - (int)(key & 0xFFFFFFFFull);
            const float bx0 = sax0[t], by0 = say0[t];
            const float bx1 = sax1[t], by1 = say1[t];
            const bool fg = maxv > FG_IOU;
            const bool bg = maxv < BG_IOU;
            const bool cross =
                (bx0 < 0.0f) || (by0 < 0.0f) || (bx1 > IMG) || (by1 > IMG);
            const size_t idx = (size_t)b * A + (base + c * CHUNK + t);
            L[idx] = cross ? -1.0f : (fg ? 1.0f : (bg ? 0.0f : -1.0f));
            float4 mbox = make_float4(0.0f, 0.0f, 0.0f, 0.0f);
            if (fg)
                mbox = make_float4(sgx0[maxg], sgy0[maxg], sgx1[maxg], sgy1[maxg]);
            M[idx] = mbox;
            V[idx] = maxv;
        }
    }

    __syncthreads();
    if (t < G) {
        // unconditional: every column must receive >= KEY_INIT (gkeys poisoned)
        atomicMax(&gkeys[b * G + t], (long long)skey[t]);
    }
}

// Rule 1 fixup: one block per batch, thread per gt. numpy scatter is
// last-write-wins; thread g writes only if no later g' targets the same anchor.
__global__ void fixup(
    const float4* __restrict__ anchors,
    const float4* __restrict__ gt,
    const long long* __restrict__ gkeys,
    float* __restrict__ L,
    float4* __restrict__ M,
    const float* __restrict__ V,
    int A) {
#pragma clang fp contract(off)
    const int b = blockIdx.x;
    const int g = threadIdx.x;
    __shared__ int tgt[G];

    unsigned long long key = (unsigned long long)gkeys[b * G + g];
    unsigned int a = 0xFFFFFFFFu - (unsigned int)(key & 0xFFFFFFFFull);
    tgt[g] = (int)a;
    __syncthreads();

    bool write = true;
    for (int g2 = g + 1; g2 < G; ++g2)
        if (tgt[g2] == (int)a) { write = false; break; }
    if (!write) return;

    const size_t idx = (size_t)b * A + a;
    float4 an = anchors[idx];
    float ax0 = an.x - 0.5f * an.z;
    float ay0 = an.y - 0.5f * an.w;
    float ax1 = an.x + 0.5f * an.z;
    float ay1 = an.y + 0.5f * an.w;
    bool cross = (ax0 < 0.0f) || (ay0 < 0.0f) || (ax1 > IMG) || (ay1 > IMG);
    // Rule 1 label=1 overrides rule-3 bg; cross filter still wins.
    L[idx] = cross ? -1.0f : 1.0f;
    // Rule 2 (fg) overrides rule 1's matched box; otherwise rule 1 assigns gt[g].
    if (!(V[idx] > FG_IOU)) M[idx] = gt[b * G + g];
}

extern "C" void kernel_launch(void* const* d_in, const int* in_sizes, int n_in,
                              void* d_out, int out_size, void* d_ws, size_t ws_size,
                              hipStream_t stream) {
    const float4* anchors = (const float4*)d_in[0];
    const float4* gt      = (const float4*)d_in[1];
    const int A = in_sizes[0] / (B * 4);

    float* out = (float*)d_out;
    float*  L = out;                                 // [B*A]
    float4* M = (float4*)(out + (size_t)B * A);      // [B*A] float4
    float*  V = out + (size_t)B * A * 5;             // [B*A]

    char* ws = (char*)d_ws;
    long long* gkeys = (long long*)(ws + 256);       // poison 0xAA.. == -inf (i64)
    unsigned long long* tabs = (unsigned long long*)(ws + 8192);  // B*4*128 u64

    const int bpb = A / ABLK;                        // 184320/768 = 240
    build_tables<<<B, 512, 0, stream>>>(gt, tabs);
    assign_main<<<B * bpb, BLOCK, 0, stream>>>(anchors, gt, L, M, V, gkeys,
                                               tabs, A, bpb);
    fixup<<<B, G, 0, stream>>>(anchors, gt, gkeys, L, M, V, A);
}

// Round 6
// 125.685 us; speedup vs baseline: 1.0419x; 1.0419x over previous
//
#include <hip/hip_runtime.h>

// RPN anchor-target assignment. B=8, A=184320, G=64.
// Outputs (flat float32, concatenated): labels[B*A], matched[B*A*4], max_iou[B*A].
// Requires A % 768 == 0 (184320 = 240*768).
//
// Sparse-mask strategy, 3 kernels (no device fences — R6: per-block fence is
// an L2-flush-scale stall). Per batch, 4 quantized interval tables (u64[128],
// 5px strips) over the 64 gts are built once; each anchor gets a conservative
// superset mask of possibly-overlapping gts (4 LDS lookups + 3 ands), then
// runs the exact IEEE IoU loop only over mask bits (~10 avg). Skipped pairs
// have true iou==0, handled exactly by maxv init 0 / KEY_INIT no-op keys.
// Column argmax via LDS u64 atomicMax; block->global via device atomicMax.
//
// History: R10 bpermute/uniform-EXEC -> 10x conflicts, REVERTED. R12 LDS
// work-queue balancing -> overhead > gain (54us, VALUBusy 48), REVERTED.
// R11 (43.4us: divergent loop + 2-way ILP + APT=3) is the base.
//
// R13 (this round): compound on R11's only-proven axis (issue trims + ILP).
//  - Single u64-mask loop, 4 pairs/iteration (was 2x 32-bit half-loops):
//    wavemax(ceil(pop/4)) iterations vs wavemax(ceil(plo/2))+wavemax(ceil(phi/2))
//    => ~15% fewer wave-max-inflated evals, 4 independent IEEE-div chains
//    interleave in the issue slots, bookkeeping amortized. Exhausted slots
//    use ctzll(m|1<<63)=63: a TRUE iou eval (out-of-mask => iou=0 => no-op;
//    re-eval idempotent under strict-> and same-key max). Ascending g with
//    dummies(=63) last => numpy first-max exact. Dummies only in a lane's
//    final iteration (<=3), unlike R10's full-tail storm.
//  - gt coords as two float2 LDS arrays (lt, rb): 2x ds_read_b64 per pair
//    (was 5x b32); gt area recomputed in-register with numpy's exact f32
//    expression (contract off).
//  - Column atomic guarded by iou>0 (zero keys are provable no-ops): removes
//    all dummy/zero LDS atomics.

constexpr int B = 8;
constexpr int G = 64;
constexpr int BLOCK = 256;
constexpr int APT = 3;                 // anchors per thread
constexpr int ABLK = BLOCK * APT;      // anchors per block = 768
constexpr int NSTRIP = 128;            // 5px strips
constexpr float STRIP_SCALE = 0.2f;
constexpr float STRIP_W = 5.0f;
constexpr float IMG = 640.0f;
constexpr float FG_IOU = 0.7f;
constexpr float BG_IOU = 0.3f;
constexpr float SLACK = 1.0f;
// key(iou=0, anchor=0): correct for an all-zero column (numpy argmax = 0).
constexpr unsigned long long KEY_INIT = 0xFFFFFFFFull;
constexpr unsigned long long TOPBIT = 0x8000000000000000ull;

// ws layout: [256]   u64 gkeys[B*G]      (0xAA poison < 0 as i64 == -inf)
//            [8192]  u64 tabs[B][4][128] (built by build_tables each launch)

// tab0 (xlo): gt.x0 < (s+1)*5 + SLACK   used at s=strip(ax1)  ⊇ gt.x0 < ax1
// tab1 (xhi): gt.x1 > s*5 - SLACK       used at s=strip(ax0)  ⊇ gt.x1 > ax0
// tab2 (ylo): gt.y0 < (s+1)*5 + SLACK   used at s=strip(ay1)  ⊇ gt.y0 < ay1
// tab3 (yhi): gt.y1 > s*5 - SLACK       used at s=strip(ay0)  ⊇ gt.y1 > ay0
__global__ __launch_bounds__(512) void build_tables(
    const float4* __restrict__ gt, unsigned long long* __restrict__ tabs) {
    __shared__ float4 sgt[G];
    const int b = blockIdx.x;
    const int t = threadIdx.x;          // 0..511 = tabIdx*128 + strip
    if (t < G) sgt[t] = gt[b * G + t];
    __syncthreads();
    const int tabIdx = t >> 7;
    const int strip = t & 127;
    const int comp = (tabIdx == 0) ? 0 : (tabIdx == 1) ? 2 : (tabIdx == 2) ? 1 : 3;
    const bool hi = (tabIdx & 1) != 0;
    const float thr = hi ? (strip * STRIP_W - SLACK)
                         : ((strip + 1) * STRIP_W + SLACK);
    unsigned long long m = 0ull;
    for (int g = 0; g < G; ++g) {
        float c = ((const float*)&sgt[g])[comp];
        bool in = hi ? (c > thr) : (c < thr);
        if (in) m |= (1ull << g);
    }
    tabs[(size_t)b * 512 + t] = m;
}

__global__ __launch_bounds__(BLOCK) void assign_main(
    const float4* __restrict__ anchors,   // [B*A] cxcywh
    const float4* __restrict__ gt,        // [B*G] xyxy
    float* __restrict__ L,                // labels out [B*A]
    float4* __restrict__ M,               // matched out [B*A]
    float* __restrict__ V,                // max_iou out [B*A]
    long long* __restrict__ gkeys,        // [B*G] global argmax keys (signed max)
    const unsigned long long* __restrict__ tabs,
    int A, int bpb) {
#pragma clang fp contract(off)
    __shared__ float2 sglt[G], sgrb[G];   // gt (x0,y0) and (x1,y1): b64 reads
    __shared__ unsigned long long tab[4][NSTRIP];
    __shared__ unsigned long long skey[G];

    const int b = blockIdx.x / bpb;
    const int t = threadIdx.x;
    const int base = (blockIdx.x % bpb) * ABLK;

    if (t < G) {
        float4 gb = gt[b * G + t];
        sglt[t] = make_float2(gb.x, gb.y);
        sgrb[t] = make_float2(gb.z, gb.w);
        skey[t] = KEY_INIT;
    }
    {   // 4 KB table: one ulonglong2 (16B) per thread
        const ulonglong2* src = (const ulonglong2*)(tabs + (size_t)b * 512);
        ((ulonglong2*)&tab[0][0])[t] = src[t];
    }
    __syncthreads();

    // All anchors' loads issued up front: later iterations' global latency
    // hides under earlier compute.
    float4 anbuf[APT];
    size_t idxs[APT];
    int as[APT];
#pragma unroll
    for (int j = 0; j < APT; ++j) {
        as[j] = base + j * BLOCK + t;
        idxs[j] = (size_t)b * A + as[j];
        anbuf[j] = anchors[idxs[j]];
    }

#pragma unroll
    for (int j = 0; j < APT; ++j) {
        const int a = as[j];
        const size_t idx = idxs[j];
        const float4 an = anbuf[j];
        const float ax0 = an.x - 0.5f * an.z;
        const float ay0 = an.y - 0.5f * an.w;
        const float ax1 = an.x + 0.5f * an.z;
        const float ay1 = an.y + 0.5f * an.w;
        const float area_a = (ax1 - ax0) * (ay1 - ay0);  // numpy corner-derived

        int sx0 = (int)(ax0 * STRIP_SCALE); sx0 = sx0 < 0 ? 0 : (sx0 > 127 ? 127 : sx0);
        int sx1 = (int)(ax1 * STRIP_SCALE); sx1 = sx1 < 0 ? 0 : (sx1 > 127 ? 127 : sx1);
        int sy0 = (int)(ay0 * STRIP_SCALE); sy0 = sy0 < 0 ? 0 : (sy0 > 127 ? 127 : sy0);
        int sy1 = (int)(ay1 * STRIP_SCALE); sy1 = sy1 < 0 ? 0 : (sy1 > 127 ? 127 : sy1);

        unsigned long long m =
            tab[0][sx1] & tab[1][sx0] & tab[2][sy1] & tab[3][sy0];

        float maxv = 0.0f;   // all-masked row => max_iou 0, argmax 0 (numpy exact)
        int maxg = 0;
        const unsigned long long inv_p =
            (unsigned long long)(0xFFFFFFFFu - (unsigned)a);

        // exact IEEE IoU for pair (this anchor, gt g): bit-exact vs numpy
        auto pair_iou = [&](int g) -> float {
            const float2 lt = sglt[g];
            const float2 rb = sgrb[g];
            const float ga = (rb.x - lt.x) * (rb.y - lt.y);  // numpy area_g
            const float lx = fmaxf(ax0, lt.x);
            const float ly = fmaxf(ay0, lt.y);
            const float rx = fminf(ax1, rb.x);
            const float ry = fminf(ay1, rb.y);
            const float w = fmaxf(rx - lx, 0.0f);
            const float h = fmaxf(ry - ly, 0.0f);
            const float inter = w * h;
            const float uni = area_a + ga - inter;
            return inter / uni;                               // IEEE div
        };

        // Divergent u64 loop, 4 pairs/iteration. Slots past the last set bit
        // extract g=63 (true iou: out-of-mask => 0 => no-op; re-eval of a
        // real bit 63 idempotent). Ascending g1<=g2<=g3<=g4 + sequential
        // strict-> updates preserve numpy first-max exactly.
        while (m) {
            const int g1 = (int)__builtin_ctzll(m);          m &= m - 1;
            const int g2 = (int)__builtin_ctzll(m | TOPBIT); m &= m - 1;
            const int g3 = (int)__builtin_ctzll(m | TOPBIT); m &= m - 1;
            const int g4 = (int)__builtin_ctzll(m | TOPBIT); m &= m - 1;

            const float i1 = pair_iou(g1);
            const float i2 = pair_iou(g2);
            const float i3 = pair_iou(g3);
            const float i4 = pair_iou(g4);

            bool b1 = i1 > maxv; maxv = b1 ? i1 : maxv; maxg = b1 ? g1 : maxg;
            bool b2 = i2 > maxv; maxv = b2 ? i2 : maxv; maxg = b2 ? g2 : maxg;
            bool b3 = i3 > maxv; maxv = b3 ? i3 : maxv; maxg = b3 ? g3 : maxg;
            bool b4 = i4 > maxv; maxv = b4 ? i4 : maxv; maxg = b4 ? g4 : maxg;

            // zero-iou keys are provable no-ops vs KEY_INIT: skip the atomic.
            if (i1 > 0.0f)
                atomicMax(&skey[g1],
                          ((unsigned long long)__float_as_uint(i1) << 32) | inv_p);
            if (i2 > 0.0f)
                atomicMax(&skey[g2],
                          ((unsigned long long)__float_as_uint(i2) << 32) | inv_p);
            if (i3 > 0.0f)
                atomicMax(&skey[g3],
                          ((unsigned long long)__float_as_uint(i3) << 32) | inv_p);
            if (i4 > 0.0f)
                atomicMax(&skey[g4],
                          ((unsigned long long)__float_as_uint(i4) << 32) | inv_p);
        }

        const bool fg = maxv > FG_IOU;
        const bool bg = maxv < BG_IOU;
        const bool cross =
            (ax0 < 0.0f) || (ay0 < 0.0f) || (ax1 > IMG) || (ay1 > IMG);

        L[idx] = cross ? -1.0f : (fg ? 1.0f : (bg ? 0.0f : -1.0f));
        float4 mbox = make_float4(0.0f, 0.0f, 0.0f, 0.0f);
        if (fg)  // rare: usually whole-wave skipped
            mbox = make_float4(sglt[maxg].x, sglt[maxg].y,
                               sgrb[maxg].x, sgrb[maxg].y);
        M[idx] = mbox;
        V[idx] = maxv;
    }

    __syncthreads();
    if (t < G) {
        // unconditional: every column must receive >= KEY_INIT (gkeys poisoned)
        atomicMax(&gkeys[b * G + t], (long long)skey[t]);
    }
}

// Rule 1 fixup: one block per batch, thread per gt. numpy scatter is
// last-write-wins; thread g writes only if no later g' targets the same anchor.
__global__ void fixup(
    const float4* __restrict__ anchors,
    const float4* __restrict__ gt,
    const long long* __restrict__ gkeys,
    float* __restrict__ L,
    float4* __restrict__ M,
    const float* __restrict__ V,
    int A) {
#pragma clang fp contract(off)
    const int b = blockIdx.x;
    const int g = threadIdx.x;
    __shared__ int tgt[G];

    unsigned long long key = (unsigned long long)gkeys[b * G + g];
    unsigned int a = 0xFFFFFFFFu - (unsigned int)(key & 0xFFFFFFFFull);
    tgt[g] = (int)a;
    __syncthreads();

    bool write = true;
    for (int g2 = g + 1; g2 < G; ++g2)
        if (tgt[g2] == (int)a) { write = false; break; }
    if (!write) return;

    const size_t idx = (size_t)b * A + a;
    float4 an = anchors[idx];
    float ax0 = an.x - 0.5f * an.z;
    float ay0 = an.y - 0.5f * an.w;
    float ax1 = an.x + 0.5f * an.z;
    float ay1 = an.y + 0.5f * an.w;
    bool cross = (ax0 < 0.0f) || (ay0 < 0.0f) || (ax1 > IMG) || (ay1 > IMG);
    // Rule 1 label=1 overrides rule-3 bg; cross filter still wins.
    L[idx] = cross ? -1.0f : 1.0f;
    // Rule 2 (fg) overrides rule 1's matched box; otherwise rule 1 assigns gt[g].
    if (!(V[idx] > FG_IOU)) M[idx] = gt[b * G + g];
}

extern "C" void kernel_launch(void* const* d_in, const int* in_sizes, int n_in,
                              void* d_out, int out_size, void* d_ws, size_t ws_size,
                              hipStream_t stream) {
    const float4* anchors = (const float4*)d_in[0];
    const float4* gt      = (const float4*)d_in[1];
    const int A = in_sizes[0] / (B * 4);

    float* out = (float*)d_out;
    float*  L = out;                                 // [B*A]
    float4* M = (float4*)(out + (size_t)B * A);      // [B*A] float4
    float*  V = out + (size_t)B * A * 5;             // [B*A]

    char* ws = (char*)d_ws;
    long long* gkeys = (long long*)(ws + 256);       // poison 0xAA.. == -inf (i64)
    unsigned long long* tabs = (unsigned long long*)(ws + 8192);  // B*4*128 u64

    const int bpb = A / ABLK;                        // 184320/768 = 240
    build_tables<<<B, 512, 0, stream>>>(gt, tabs);
    assign_main<<<B * bpb, BLOCK, 0, stream>>>(anchors, gt, L, M, V, gkeys,
                                               tabs, A, bpb);
    fixup<<<B, G, 0, stream>>>(anchors, gt, gkeys, L, M, V, A);
}

// Round 8
// 116.929 us; speedup vs baseline: 1.1199x; 1.0749x over previous
//
#include <hip/hip_runtime.h>

// RPN anchor-target assignment. B=8, A=184320, G=64.
// Outputs (flat float32, concatenated): labels[B*A], matched[B*A*4], max_iou[B*A].
// Requires A % 768 == 0 (184320 = 240*768).
//
// Sparse-mask strategy, 3 kernels. Per batch, 4 quantized interval tables
// (u64[128], 5px strips) over the 64 gts; each anchor gets a conservative
// superset mask of possibly-overlapping gts, then exact IEEE IoU only over
// mask bits (~10 avg). Skipped pairs have true iou==0 (exact via KEY_INIT /
// maxv=0 no-ops). Column argmax via LDS u64 atomicMax (order-free exact key);
// block->global via device atomicMax.
//
// History: R10 bpermute/uniform-EXEC -> 10x conflicts, REVERTED. R12 per-PAIR
// work-queue -> machinery cost > gain, REVERTED. R13 float2-b64 reads (16-bank
// 4-way conflicts) + VALU-area + 4-way dummies -> REVERTED. Base = R11
// (43.4us: b32 SoA gt reads, divergent loop, 2-way ILP, APT=3).
//
// R14 (resubmit — R7's bench died on container acquire, no kernel signal):
// anchor-grain load balancing via in-block popcount counting-sort (~10x
// lighter than R12's per-pair queue).
//  Diagnosis: divergent loop runs wave-max pop (~18) vs lane-mean (~10) ->
//  ~half the issued VALU cycles are exec-masked. Fix: per block, build all
//  768 masks first (stored u64 in LDS + corner SoA), histogram popcounts
//  (64 bins, clamp), one-wave shfl exclusive scan, slot-alloc via atomicAdd,
//  then consume anchors in sorted order: thread t takes sorted slots
//  {t, t+256, t+512} (stratified -> per-thread totals balanced; per-wave
//  rounds near-uniform pop -> wavemax ~ mean).
//  - Column key (iou, 0xFFFFFFFF-a) is a total order -> processing order
//    irrelevant (numpy first-max = smallest a on ties, encoded in key).
//  - Row argmax: merged u64 mask loop, 2 pairs/iter, ascending g, strict >,
//    odd tail duplicates last real bit (idempotent) -> numpy-exact.
//  - gt + anchor-corner reads stay scalar b32 (R7/R13 lesson: wide-gather
//    LDS reads at random indices are 4-8 way bank-conflicted).
//  - Outputs scatter within the block's 768-anchor window: L2 absorbs,
//    lines fully covered -> WRITE_SIZE unchanged.

constexpr int B = 8;
constexpr int G = 64;
constexpr int BLOCK = 256;
constexpr int APT = 3;                 // anchors per thread
constexpr int ABLK = BLOCK * APT;      // anchors per block = 768
constexpr int NSTRIP = 128;            // 5px strips
constexpr float STRIP_SCALE = 0.2f;
constexpr float STRIP_W = 5.0f;
constexpr float IMG = 640.0f;
constexpr float FG_IOU = 0.7f;
constexpr float BG_IOU = 0.3f;
constexpr float SLACK = 1.0f;
// key(iou=0, anchor=0): correct for an all-zero column (numpy argmax = 0).
constexpr unsigned long long KEY_INIT = 0xFFFFFFFFull;
constexpr unsigned long long TOPBIT = 0x8000000000000000ull;

// ws layout: [256]   u64 gkeys[B*G]      (0xAA poison < 0 as i64 == -inf)
//            [8192]  u64 tabs[B][4][128] (built by build_tables each launch)

// tab0 (xlo): gt.x0 < (s+1)*5 + SLACK   used at s=strip(ax1)  ⊇ gt.x0 < ax1
// tab1 (xhi): gt.x1 > s*5 - SLACK       used at s=strip(ax0)  ⊇ gt.x1 > ax0
// tab2 (ylo): gt.y0 < (s+1)*5 + SLACK   used at s=strip(ay1)  ⊇ gt.y0 < ay1
// tab3 (yhi): gt.y1 > s*5 - SLACK       used at s=strip(ay0)  ⊇ gt.y1 > ay0
__global__ __launch_bounds__(512) void build_tables(
    const float4* __restrict__ gt, unsigned long long* __restrict__ tabs) {
    __shared__ float4 sgt[G];
    const int b = blockIdx.x;
    const int t = threadIdx.x;          // 0..511 = tabIdx*128 + strip
    if (t < G) sgt[t] = gt[b * G + t];
    __syncthreads();
    const int tabIdx = t >> 7;
    const int strip = t & 127;
    const int comp = (tabIdx == 0) ? 0 : (tabIdx == 1) ? 2 : (tabIdx == 2) ? 1 : 3;
    const bool hi = (tabIdx & 1) != 0;
    const float thr = hi ? (strip * STRIP_W - SLACK)
                         : ((strip + 1) * STRIP_W + SLACK);
    unsigned long long m = 0ull;
    for (int g = 0; g < G; ++g) {
        float c = ((const float*)&sgt[g])[comp];
        bool in = hi ? (c > thr) : (c < thr);
        if (in) m |= (1ull << g);
    }
    tabs[(size_t)b * 512 + t] = m;
}

__global__ __launch_bounds__(BLOCK) void assign_main(
    const float4* __restrict__ anchors,   // [B*A] cxcywh
    const float4* __restrict__ gt,        // [B*G] xyxy
    float* __restrict__ L,                // labels out [B*A]
    float4* __restrict__ M,               // matched out [B*A]
    float* __restrict__ V,                // max_iou out [B*A]
    long long* __restrict__ gkeys,        // [B*G] global argmax keys (signed max)
    const unsigned long long* __restrict__ tabs,
    int A, int bpb) {
#pragma clang fp contract(off)
    __shared__ float sgx0[G], sgy0[G], sgx1[G], sgy1[G], sga[G];  // gt SoA
    __shared__ unsigned long long tab[4][NSTRIP];                 // 4 KB
    __shared__ unsigned long long skey[G];                        // col keys
    __shared__ float sax0[ABLK], say0[ABLK], sax1[ABLK], say1[ABLK]; // 12 KB
    __shared__ unsigned long long smask[ABLK];                    // 6 KB
    __shared__ unsigned short sidx[ABLK];                         // 1.5 KB
    __shared__ int hist[G];                                       // counts
    __shared__ int pfx[G];                                        // prefix/alloc

    const int b = blockIdx.x / bpb;
    const int t = threadIdx.x;
    const int base = (blockIdx.x % bpb) * ABLK;

    if (t < G) {
        float4 gb = gt[b * G + t];
        sgx0[t] = gb.x; sgy0[t] = gb.y; sgx1[t] = gb.z; sgy1[t] = gb.w;
        sga[t] = (gb.z - gb.x) * (gb.w - gb.y);
        skey[t] = KEY_INIT;
        hist[t] = 0;
    }
    {   // 4 KB table: one ulonglong2 (16B) per thread
        const ulonglong2* src = (const ulonglong2*)(tabs + (size_t)b * 512);
        ((ulonglong2*)&tab[0][0])[t] = src[t];
    }

    // Prefetch this thread's anchors (global latency hides under staging).
    float4 anbuf[APT];
#pragma unroll
    for (int j = 0; j < APT; ++j)
        anbuf[j] = anchors[(size_t)b * A + base + j * BLOCK + t];

    __syncthreads();   // tab ready

    // ---- build: corners, masks, popcount histogram ----
    int pops[APT];
#pragma unroll
    for (int j = 0; j < APT; ++j) {
        const int k = j * BLOCK + t;
        const float4 an = anbuf[j];
        const float ax0 = an.x - 0.5f * an.z;
        const float ay0 = an.y - 0.5f * an.w;
        const float ax1 = an.x + 0.5f * an.z;
        const float ay1 = an.y + 0.5f * an.w;
        sax0[k] = ax0; say0[k] = ay0; sax1[k] = ax1; say1[k] = ay1;

        int sx0 = (int)(ax0 * STRIP_SCALE); sx0 = sx0 < 0 ? 0 : (sx0 > 127 ? 127 : sx0);
        int sx1 = (int)(ax1 * STRIP_SCALE); sx1 = sx1 < 0 ? 0 : (sx1 > 127 ? 127 : sx1);
        int sy0 = (int)(ay0 * STRIP_SCALE); sy0 = sy0 < 0 ? 0 : (sy0 > 127 ? 127 : sy0);
        int sy1 = (int)(ay1 * STRIP_SCALE); sy1 = sy1 < 0 ? 0 : (sy1 > 127 ? 127 : sy1);
        const unsigned long long mask =
            tab[0][sx1] & tab[1][sx0] & tab[2][sy1] & tab[3][sy0];
        smask[k] = mask;
        pops[j] = __builtin_popcountll(mask);
        atomicAdd(&hist[pops[j] > 63 ? 63 : pops[j]], 1);
    }
    __syncthreads();

    // ---- one-wave exclusive scan of 64-bin histogram ----
    if (t < G) {
        const int c0 = hist[t];
        int x = c0;
#pragma unroll
        for (int d = 1; d < 64; d <<= 1) {
            int y = __shfl_up(x, d, 64);
            if (t >= d) x += y;
        }
        pfx[t] = x - c0;   // exclusive prefix
    }
    __syncthreads();

    // ---- slot allocation: sorted-by-popcount order ----
#pragma unroll
    for (int j = 0; j < APT; ++j) {
        const int bin = pops[j] > 63 ? 63 : pops[j];
        const int pos = atomicAdd(&pfx[bin], 1);
        sidx[pos] = (unsigned short)(j * BLOCK + t);
    }
    __syncthreads();

    // ---- consume: stratified sorted order; wave pops near-uniform ----
#pragma unroll
    for (int r = 0; r < APT; ++r) {
        const int k = (int)sidx[r * BLOCK + t];
        const int a = base + k;                      // within-batch anchor id
        const size_t idx = (size_t)b * A + a;
        const float ax0 = sax0[k], ay0 = say0[k];
        const float ax1 = sax1[k], ay1 = say1[k];
        const float area_a = (ax1 - ax0) * (ay1 - ay0);  // numpy corner-derived
        unsigned long long m = smask[k];

        float maxv = 0.0f;   // all-masked row => max_iou 0, argmax 0 (numpy)
        int maxg = 0;
        const unsigned long long inv_p =
            (unsigned long long)(0xFFFFFFFFu - (unsigned)a);

        // merged u64 loop, 2 pairs/iter, ascending g, odd tail duplicates the
        // last real bit (idempotent under strict > and same-key atomicMax).
        while (m) {
            const int g1 = (int)__builtin_ctzll(m);          m &= m - 1;
            const int cand = (int)__builtin_ctzll(m | TOPBIT);
            const int g2 = m ? cand : g1;                    m &= m - 1;

            const float gx0a = sgx0[g1], gy0a = sgy0[g1];
            const float gx1a = sgx1[g1], gy1a = sgy1[g1];
            const float saa  = sga[g1];
            const float gx0b = sgx0[g2], gy0b = sgy0[g2];
            const float gx1b = sgx1[g2], gy1b = sgy1[g2];
            const float sab  = sga[g2];

            float lxa = fmaxf(ax0, gx0a), lya = fmaxf(ay0, gy0a);
            float rxa = fminf(ax1, gx1a), rya = fminf(ay1, gy1a);
            float wa = fmaxf(rxa - lxa, 0.0f), ha = fmaxf(rya - lya, 0.0f);
            float intera = wa * ha;
            float unia = area_a + saa - intera;
            float ioua = intera / unia;          // IEEE div: bit-exact vs numpy

            float lxb = fmaxf(ax0, gx0b), lyb = fmaxf(ay0, gy0b);
            float rxb = fminf(ax1, gx1b), ryb = fminf(ay1, gy1b);
            float wb = fmaxf(rxb - lxb, 0.0f), hb = fmaxf(ryb - lyb, 0.0f);
            float interb = wb * hb;
            float unib = area_a + sab - interb;
            float ioub = interb / unib;          // IEEE div: bit-exact vs numpy

            bool b1 = ioua > maxv; maxv = b1 ? ioua : maxv; maxg = b1 ? g1 : maxg;
            bool b2 = ioub > maxv; maxv = b2 ? ioub : maxv; maxg = b2 ? g2 : maxg;

            // iou==0 => key = inv_p <= KEY_INIT: atomicMax natural no-op.
            unsigned long long key1 =
                ((unsigned long long)__float_as_uint(ioua) << 32) | inv_p;
            unsigned long long key2 =
                ((unsigned long long)__float_as_uint(ioub) << 32) | inv_p;
            atomicMax(&skey[g1], key1);
            atomicMax(&skey[g2], key2);
        }

        const bool fg = maxv > FG_IOU;
        const bool bg = maxv < BG_IOU;
        const bool cross =
            (ax0 < 0.0f) || (ay0 < 0.0f) || (ax1 > IMG) || (ay1 > IMG);

        L[idx] = cross ? -1.0f : (fg ? 1.0f : (bg ? 0.0f : -1.0f));
        float4 mbox = make_float4(0.0f, 0.0f, 0.0f, 0.0f);
        if (fg)  // rare: usually whole-wave skipped; SoA gather (4 b32 reads)
            mbox = make_float4(sgx0[maxg], sgy0[maxg], sgx1[maxg], sgy1[maxg]);
        M[idx] = mbox;
        V[idx] = maxv;
    }

    __syncthreads();
    if (t < G) {
        // unconditional: every column must receive >= KEY_INIT (gkeys poisoned)
        atomicMax(&gkeys[b * G + t], (long long)skey[t]);
    }
}

// Rule 1 fixup: one block per batch, thread per gt. numpy scatter is
// last-write-wins; thread g writes only if no later g' targets the same anchor.
__global__ void fixup(
    const float4* __restrict__ anchors,
    const float4* __restrict__ gt,
    const long long* __restrict__ gkeys,
    float* __restrict__ L,
    float4* __restrict__ M,
    const float* __restrict__ V,
    int A) {
#pragma clang fp contract(off)
    const int b = blockIdx.x;
    const int g = threadIdx.x;
    __shared__ int tgt[G];

    unsigned long long key = (unsigned long long)gkeys[b * G + g];
    unsigned int a = 0xFFFFFFFFu - (unsigned int)(key & 0xFFFFFFFFull);
    tgt[g] = (int)a;
    __syncthreads();

    bool write = true;
    for (int g2 = g + 1; g2 < G; ++g2)
        if (tgt[g2] == (int)a) { write = false; break; }
    if (!write) return;

    const size_t idx = (size_t)b * A + a;
    float4 an = anchors[idx];
    float ax0 = an.x - 0.5f * an.z;
    float ay0 = an.y - 0.5f * an.w;
    float ax1 = an.x + 0.5f * an.z;
    float ay1 = an.y + 0.5f * an.w;
    bool cross = (ax0 < 0.0f) || (ay0 < 0.0f) || (ax1 > IMG) || (ay1 > IMG);
    // Rule 1 label=1 overrides rule-3 bg; cross filter still wins.
    L[idx] = cross ? -1.0f : 1.0f;
    // Rule 2 (fg) overrides rule 1's matched box; otherwise rule 1 assigns gt[g].
    if (!(V[idx] > FG_IOU)) M[idx] = gt[b * G + g];
}

extern "C" void kernel_launch(void* const* d_in, const int* in_sizes, int n_in,
                              void* d_out, int out_size, void* d_ws, size_t ws_size,
                              hipStream_t stream) {
    const float4* anchors = (const float4*)d_in[0];
    const float4* gt      = (const float4*)d_in[1];
    const int A = in_sizes[0] / (B * 4);

    float* out = (float*)d_out;
    float*  L = out;                                 // [B*A]
    float4* M = (float4*)(out + (size_t)B * A);      // [B*A] float4
    float*  V = out + (size_t)B * A * 5;             // [B*A]

    char* ws = (char*)d_ws;
    long long* gkeys = (long long*)(ws + 256);       // poison 0xAA.. == -inf (i64)
    unsigned long long* tabs = (unsigned long long*)(ws + 8192);  // B*4*128 u64

    const int bpb = A / ABLK;                        // 184320/768 = 240
    build_tables<<<B, 512, 0, stream>>>(gt, tabs);
    assign_main<<<B * bpb, BLOCK, 0, stream>>>(anchors, gt, L, M, V, gkeys,
                                               tabs, A, bpb);
    fixup<<<B, G, 0, stream>>>(anchors, gt, gkeys, L, M, V, A);
}

// Round 9
// 114.827 us; speedup vs baseline: 1.1404x; 1.0183x over previous
//
#include <hip/hip_runtime.h>

// RPN anchor-target assignment. B=8, A=184320, G=64.
// Outputs (flat float32, concatenated): labels[B*A], matched[B*A*4], max_iou[B*A].
// Requires A % 768 == 0 (184320 = 240*768).
//
// Sparse-mask strategy, 3 kernels. Per batch, 4 quantized interval tables
// (u64[128], 5px strips) over the 64 gts; each anchor gets a conservative
// superset mask of possibly-overlapping gts, then exact IEEE IoU only over
// mask bits (~10 avg). Skipped pairs have true iou==0 (exact via KEY_INIT /
// maxv=0 no-ops). Column argmax via LDS u64 atomicMax (order-free exact key);
// block->global via device atomicMax.
//
// History: R10 bpermute -> REVERTED. R12 per-pair queue -> REVERTED.
// R13 b64 gt reads + 4-way dummies -> REVERTED. R14 anchor-grain popcount
// counting-sort balancing -> WIN (43.4 -> ~40us, total 122 -> 116.9).
//
// R15 (this round): occupancy 47% -> ~94% by fitting 8 blocks/CU.
//  Diagnosis: issued VALU work is only ~9us worth; kernel runs ~40us ->
//  latency-bound at 3.7 waves/SIMD (LDS 26.1KB caps 6 blocks/CU; grid 1920
//  wants 7.5 -> ragged second round, 47% time-avg occupancy).
//  Fix: drop the 6KB smask[] LDS array; consume RECOMPUTES the mask from the
//  staged corners + tab (identical deterministic inputs -> identical mask;
//  +4 scattered u64 tab reads + ~16 VALU per ANCHOR, trivial vs the win).
//  LDS 26368 -> 20224 B <= 20480 -> 8 blocks/CU; all 1920 blocks resident in
//  ONE round. __launch_bounds__(256,8) pins VGPR <= 64 for 8 waves/SIMD.

constexpr int B = 8;
constexpr int G = 64;
constexpr int BLOCK = 256;
constexpr int APT = 3;                 // anchors per thread
constexpr int ABLK = BLOCK * APT;      // anchors per block = 768
constexpr int NSTRIP = 128;            // 5px strips
constexpr float STRIP_SCALE = 0.2f;
constexpr float STRIP_W = 5.0f;
constexpr float IMG = 640.0f;
constexpr float FG_IOU = 0.7f;
constexpr float BG_IOU = 0.3f;
constexpr float SLACK = 1.0f;
// key(iou=0, anchor=0): correct for an all-zero column (numpy argmax = 0).
constexpr unsigned long long KEY_INIT = 0xFFFFFFFFull;
constexpr unsigned long long TOPBIT = 0x8000000000000000ull;

// ws layout: [256]   u64 gkeys[B*G]      (0xAA poison < 0 as i64 == -inf)
//            [8192]  u64 tabs[B][4][128] (built by build_tables each launch)

// tab0 (xlo): gt.x0 < (s+1)*5 + SLACK   used at s=strip(ax1)  ⊇ gt.x0 < ax1
// tab1 (xhi): gt.x1 > s*5 - SLACK       used at s=strip(ax0)  ⊇ gt.x1 > ax0
// tab2 (ylo): gt.y0 < (s+1)*5 + SLACK   used at s=strip(ay1)  ⊇ gt.y0 < ay1
// tab3 (yhi): gt.y1 > s*5 - SLACK       used at s=strip(ay0)  ⊇ gt.y1 > ay0
__global__ __launch_bounds__(512) void build_tables(
    const float4* __restrict__ gt, unsigned long long* __restrict__ tabs) {
    __shared__ float4 sgt[G];
    const int b = blockIdx.x;
    const int t = threadIdx.x;          // 0..511 = tabIdx*128 + strip
    if (t < G) sgt[t] = gt[b * G + t];
    __syncthreads();
    const int tabIdx = t >> 7;
    const int strip = t & 127;
    const int comp = (tabIdx == 0) ? 0 : (tabIdx == 1) ? 2 : (tabIdx == 2) ? 1 : 3;
    const bool hi = (tabIdx & 1) != 0;
    const float thr = hi ? (strip * STRIP_W - SLACK)
                         : ((strip + 1) * STRIP_W + SLACK);
    unsigned long long m = 0ull;
    for (int g = 0; g < G; ++g) {
        float c = ((const float*)&sgt[g])[comp];
        bool in = hi ? (c > thr) : (c < thr);
        if (in) m |= (1ull << g);
    }
    tabs[(size_t)b * 512 + t] = m;
}

__device__ __forceinline__ int stripclamp(float v) {
    int s = (int)(v * STRIP_SCALE);
    return s < 0 ? 0 : (s > 127 ? 127 : s);
}

__global__ __launch_bounds__(BLOCK, 8) void assign_main(
    const float4* __restrict__ anchors,   // [B*A] cxcywh
    const float4* __restrict__ gt,        // [B*G] xyxy
    float* __restrict__ L,                // labels out [B*A]
    float4* __restrict__ M,               // matched out [B*A]
    float* __restrict__ V,                // max_iou out [B*A]
    long long* __restrict__ gkeys,        // [B*G] global argmax keys (signed max)
    const unsigned long long* __restrict__ tabs,
    int A, int bpb) {
#pragma clang fp contract(off)
    __shared__ float sgx0[G], sgy0[G], sgx1[G], sgy1[G], sga[G];  // gt SoA
    __shared__ unsigned long long tab[4][NSTRIP];                 // 4 KB
    __shared__ unsigned long long skey[G];                        // col keys
    __shared__ float sax0[ABLK], say0[ABLK], sax1[ABLK], say1[ABLK]; // 12 KB
    __shared__ unsigned short sidx[ABLK];                         // 1.5 KB
    __shared__ int hist[G];                                       // counts
    __shared__ int pfx[G];                                        // prefix/alloc

    const int b = blockIdx.x / bpb;
    const int t = threadIdx.x;
    const int base = (blockIdx.x % bpb) * ABLK;

    if (t < G) {
        float4 gb = gt[b * G + t];
        sgx0[t] = gb.x; sgy0[t] = gb.y; sgx1[t] = gb.z; sgy1[t] = gb.w;
        sga[t] = (gb.z - gb.x) * (gb.w - gb.y);
        skey[t] = KEY_INIT;
        hist[t] = 0;
    }
    {   // 4 KB table: one ulonglong2 (16B) per thread
        const ulonglong2* src = (const ulonglong2*)(tabs + (size_t)b * 512);
        ((ulonglong2*)&tab[0][0])[t] = src[t];
    }

    // Prefetch this thread's anchors (global latency hides under staging).
    float4 anbuf[APT];
#pragma unroll
    for (int j = 0; j < APT; ++j)
        anbuf[j] = anchors[(size_t)b * A + base + j * BLOCK + t];

    __syncthreads();   // tab ready

    // ---- build: corners + popcount histogram (mask NOT stored: consume
    //      recomputes it from identical inputs -> identical bits) ----
    int pops[APT];
#pragma unroll
    for (int j = 0; j < APT; ++j) {
        const int k = j * BLOCK + t;
        const float4 an = anbuf[j];
        const float ax0 = an.x - 0.5f * an.z;
        const float ay0 = an.y - 0.5f * an.w;
        const float ax1 = an.x + 0.5f * an.z;
        const float ay1 = an.y + 0.5f * an.w;
        sax0[k] = ax0; say0[k] = ay0; sax1[k] = ax1; say1[k] = ay1;

        const unsigned long long mask =
            tab[0][stripclamp(ax1)] & tab[1][stripclamp(ax0)] &
            tab[2][stripclamp(ay1)] & tab[3][stripclamp(ay0)];
        pops[j] = __builtin_popcountll(mask);
        atomicAdd(&hist[pops[j] > 63 ? 63 : pops[j]], 1);
    }
    __syncthreads();

    // ---- one-wave exclusive scan of 64-bin histogram ----
    if (t < G) {
        const int c0 = hist[t];
        int x = c0;
#pragma unroll
        for (int d = 1; d < 64; d <<= 1) {
            int y = __shfl_up(x, d, 64);
            if (t >= d) x += y;
        }
        pfx[t] = x - c0;   // exclusive prefix
    }
    __syncthreads();

    // ---- slot allocation: sorted-by-popcount order ----
#pragma unroll
    for (int j = 0; j < APT; ++j) {
        const int bin = pops[j] > 63 ? 63 : pops[j];
        const int pos = atomicAdd(&pfx[bin], 1);
        sidx[pos] = (unsigned short)(j * BLOCK + t);
    }
    __syncthreads();

    // ---- consume: stratified sorted order; wave pops near-uniform ----
#pragma unroll
    for (int r = 0; r < APT; ++r) {
        const int k = (int)sidx[r * BLOCK + t];
        const int a = base + k;                      // within-batch anchor id
        const size_t idx = (size_t)b * A + a;
        const float ax0 = sax0[k], ay0 = say0[k];
        const float ax1 = sax1[k], ay1 = say1[k];
        const float area_a = (ax1 - ax0) * (ay1 - ay0);  // numpy corner-derived

        // recompute mask (bit-identical to build's: same corners, same tab)
        unsigned long long m =
            tab[0][stripclamp(ax1)] & tab[1][stripclamp(ax0)] &
            tab[2][stripclamp(ay1)] & tab[3][stripclamp(ay0)];

        float maxv = 0.0f;   // all-masked row => max_iou 0, argmax 0 (numpy)
        int maxg = 0;
        const unsigned long long inv_p =
            (unsigned long long)(0xFFFFFFFFu - (unsigned)a);

        // merged u64 loop, 2 pairs/iter, ascending g, odd tail duplicates the
        // last real bit (idempotent under strict > and same-key atomicMax).
        while (m) {
            const int g1 = (int)__builtin_ctzll(m);          m &= m - 1;
            const int cand = (int)__builtin_ctzll(m | TOPBIT);
            const int g2 = m ? cand : g1;                    m &= m - 1;

            const float gx0a = sgx0[g1], gy0a = sgy0[g1];
            const float gx1a = sgx1[g1], gy1a = sgy1[g1];
            const float saa  = sga[g1];
            const float gx0b = sgx0[g2], gy0b = sgy0[g2];
            const float gx1b = sgx1[g2], gy1b = sgy1[g2];
            const float sab  = sga[g2];

            float lxa = fmaxf(ax0, gx0a), lya = fmaxf(ay0, gy0a);
            float rxa = fminf(ax1, gx1a), rya = fminf(ay1, gy1a);
            float wa = fmaxf(rxa - lxa, 0.0f), ha = fmaxf(rya - lya, 0.0f);
            float intera = wa * ha;
            float unia = area_a + saa - intera;
            float ioua = intera / unia;          // IEEE div: bit-exact vs numpy

            float lxb = fmaxf(ax0, gx0b), lyb = fmaxf(ay0, gy0b);
            float rxb = fminf(ax1, gx1b), ryb = fminf(ay1, gy1b);
            float wb = fmaxf(rxb - lxb, 0.0f), hb = fmaxf(ryb - lyb, 0.0f);
            float interb = wb * hb;
            float unib = area_a + sab - interb;
            float ioub = interb / unib;          // IEEE div: bit-exact vs numpy

            bool b1 = ioua > maxv; maxv = b1 ? ioua : maxv; maxg = b1 ? g1 : maxg;
            bool b2 = ioub > maxv; maxv = b2 ? ioub : maxv; maxg = b2 ? g2 : maxg;

            // iou==0 => key = inv_p <= KEY_INIT: atomicMax natural no-op.
            unsigned long long key1 =
                ((unsigned long long)__float_as_uint(ioua) << 32) | inv_p;
            unsigned long long key2 =
                ((unsigned long long)__float_as_uint(ioub) << 32) | inv_p;
            atomicMax(&skey[g1], key1);
            atomicMax(&skey[g2], key2);
        }

        const bool fg = maxv > FG_IOU;
        const bool bg = maxv < BG_IOU;
        const bool cross =
            (ax0 < 0.0f) || (ay0 < 0.0f) || (ax1 > IMG) || (ay1 > IMG);

        L[idx] = cross ? -1.0f : (fg ? 1.0f : (bg ? 0.0f : -1.0f));
        float4 mbox = make_float4(0.0f, 0.0f, 0.0f, 0.0f);
        if (fg)  // rare: usually whole-wave skipped; SoA gather (4 b32 reads)
            mbox = make_float4(sgx0[maxg], sgy0[maxg], sgx1[maxg], sgy1[maxg]);
        M[idx] = mbox;
        V[idx] = maxv;
    }

    __syncthreads();
    if (t < G) {
        // unconditional: every column must receive >= KEY_INIT (gkeys poisoned)
        atomicMax(&gkeys[b * G + t], (long long)skey[t]);
    }
}

// Rule 1 fixup: one block per batch, thread per gt. numpy scatter is
// last-write-wins; thread g writes only if no later g' targets the same anchor.
__global__ void fixup(
    const float4* __restrict__ anchors,
    const float4* __restrict__ gt,
    const long long* __restrict__ gkeys,
    float* __restrict__ L,
    float4* __restrict__ M,
    const float* __restrict__ V,
    int A) {
#pragma clang fp contract(off)
    const int b = blockIdx.x;
    const int g = threadIdx.x;
    __shared__ int tgt[G];

    unsigned long long key = (unsigned long long)gkeys[b * G + g];
    unsigned int a = 0xFFFFFFFFu - (unsigned int)(key & 0xFFFFFFFFull);
    tgt[g] = (int)a;
    __syncthreads();

    bool write = true;
    for (int g2 = g + 1; g2 < G; ++g2)
        if (tgt[g2] == (int)a) { write = false; break; }
    if (!write) return;

    const size_t idx = (size_t)b * A + a;
    float4 an = anchors[idx];
    float ax0 = an.x - 0.5f * an.z;
    float ay0 = an.y - 0.5f * an.w;
    float ax1 = an.x + 0.5f * an.z;
    float ay1 = an.y + 0.5f * an.w;
    bool cross = (ax0 < 0.0f) || (ay0 < 0.0f) || (ax1 > IMG) || (ay1 > IMG);
    // Rule 1 label=1 overrides rule-3 bg; cross filter still wins.
    L[idx] = cross ? -1.0f : 1.0f;
    // Rule 2 (fg) overrides rule 1's matched box; otherwise rule 1 assigns gt[g].
    if (!(V[idx] > FG_IOU)) M[idx] = gt[b * G + g];
}

extern "C" void kernel_launch(void* const* d_in, const int* in_sizes, int n_in,
                              void* d_out, int out_size, void* d_ws, size_t ws_size,
                              hipStream_t stream) {
    const float4* anchors = (const float4*)d_in[0];
    const float4* gt      = (const float4*)d_in[1];
    const int A = in_sizes[0] / (B * 4);

    float* out = (float*)d_out;
    float*  L = out;                                 // [B*A]
    float4* M = (float4*)(out + (size_t)B * A);      // [B*A] float4
    float*  V = out + (size_t)B * A * 5;             // [B*A]

    char* ws = (char*)d_ws;
    long long* gkeys = (long long*)(ws + 256);       // poison 0xAA.. == -inf (i64)
    unsigned long long* tabs = (unsigned long long*)(ws + 8192);  // B*4*128 u64

    const int bpb = A / ABLK;                        // 184320/768 = 240
    build_tables<<<B, 512, 0, stream>>>(gt, tabs);
    assign_main<<<B * bpb, BLOCK, 0, stream>>>(anchors, gt, L, M, V, gkeys,
                                               tabs, A, bpb);
    fixup<<<B, G, 0, stream>>>(anchors, gt, gkeys, L, M, V, A);
}

// Round 10
// 113.300 us; speedup vs baseline: 1.1558x; 1.0135x over previous
//
#include <hip/hip_runtime.h>

// RPN anchor-target assignment. B=8, A=184320, G=64.
// Outputs (flat float32, concatenated): labels[B*A], matched[B*A*4], max_iou[B*A].
// Requires A % 768 == 0 (184320 = 240*768).
//
// Sparse-mask strategy, 3 kernels. Per batch, 4 quantized interval tables
// (u64[128], 5px strips) over the 64 gts; each anchor gets a conservative
// superset mask of possibly-overlapping gts, then exact IEEE IoU only over
// mask bits (~10 avg, near-exact vs true overlap count). Column argmax via
// LDS u64 atomicMax (order-free exact key); block->global device atomicMax.
//
// History: R10 bpermute -> REVERTED. R12 per-pair queue -> REVERTED. R13
// b64+dummies (confounded) -> REVERTED. R14 popcount counting-sort balancing
// -> WIN (~40us). R15 8 blocks/CU via dropping smask[] -> small win (~38us);
// occupancy was NOT the binding constraint.
//
// R16 (this round): assign_main is LDS-PIPE-THROUGHPUT-bound.
//  Model: ~115K two-pair wave-iters x 12 LDS ops (10 scattered b32 gt reads
//  + 2 atomics) ~ 42K DS-pipe cyc/CU ~ 18us, + staging/mask/atomics -> ~38us
//  observed (issue-bound floor would be ~8us). Conflicts are the minor term
//  (~4us); OP COUNT is the lever.
//  Fix: gt stored as ONE float4[G] AoS array; per pair ONE ds_read_b128
//  (was 5x b32) + VALU area recompute (g.z-g.x)*(g.w-g.y) — numpy's exact
//  expression, contract(off) -> bit-exact. Per 2-pair iter: 12 -> 4 LDS ops.
//  Clean single-axis A/B vs R15 (R13's b64 test was confounded with dummy
//  pairs). Expected: conflict COUNTER rises (b128 gather ~8-way, R7 PMC)
//  while total DS-pipe cycles and duration fall.

constexpr int B = 8;
constexpr int G = 64;
constexpr int BLOCK = 256;
constexpr int APT = 3;                 // anchors per thread
constexpr int ABLK = BLOCK * APT;      // anchors per block = 768
constexpr int NSTRIP = 128;            // 5px strips
constexpr float STRIP_SCALE = 0.2f;
constexpr float STRIP_W = 5.0f;
constexpr float IMG = 640.0f;
constexpr float FG_IOU = 0.7f;
constexpr float BG_IOU = 0.3f;
constexpr float SLACK = 1.0f;
// key(iou=0, anchor=0): correct for an all-zero column (numpy argmax = 0).
constexpr unsigned long long KEY_INIT = 0xFFFFFFFFull;
constexpr unsigned long long TOPBIT = 0x8000000000000000ull;

// ws layout: [256]   u64 gkeys[B*G]      (0xAA poison < 0 as i64 == -inf)
//            [8192]  u64 tabs[B][4][128] (built by build_tables each launch)

// tab0 (xlo): gt.x0 < (s+1)*5 + SLACK   used at s=strip(ax1)  ⊇ gt.x0 < ax1
// tab1 (xhi): gt.x1 > s*5 - SLACK       used at s=strip(ax0)  ⊇ gt.x1 > ax0
// tab2 (ylo): gt.y0 < (s+1)*5 + SLACK   used at s=strip(ay1)  ⊇ gt.y0 < ay1
// tab3 (yhi): gt.y1 > s*5 - SLACK       used at s=strip(ay0)  ⊇ gt.y1 > ay0
__global__ __launch_bounds__(512) void build_tables(
    const float4* __restrict__ gt, unsigned long long* __restrict__ tabs) {
    __shared__ float4 sgt[G];
    const int b = blockIdx.x;
    const int t = threadIdx.x;          // 0..511 = tabIdx*128 + strip
    if (t < G) sgt[t] = gt[b * G + t];
    __syncthreads();
    const int tabIdx = t >> 7;
    const int strip = t & 127;
    const int comp = (tabIdx == 0) ? 0 : (tabIdx == 1) ? 2 : (tabIdx == 2) ? 1 : 3;
    const bool hi = (tabIdx & 1) != 0;
    const float thr = hi ? (strip * STRIP_W - SLACK)
                         : ((strip + 1) * STRIP_W + SLACK);
    unsigned long long m = 0ull;
    for (int g = 0; g < G; ++g) {
        float c = ((const float*)&sgt[g])[comp];
        bool in = hi ? (c > thr) : (c < thr);
        if (in) m |= (1ull << g);
    }
    tabs[(size_t)b * 512 + t] = m;
}

__device__ __forceinline__ int stripclamp(float v) {
    int s = (int)(v * STRIP_SCALE);
    return s < 0 ? 0 : (s > 127 ? 127 : s);
}

__global__ __launch_bounds__(BLOCK, 8) void assign_main(
    const float4* __restrict__ anchors,   // [B*A] cxcywh
    const float4* __restrict__ gt,        // [B*G] xyxy
    float* __restrict__ L,                // labels out [B*A]
    float4* __restrict__ M,               // matched out [B*A]
    float* __restrict__ V,                // max_iou out [B*A]
    long long* __restrict__ gkeys,        // [B*G] global argmax keys (signed max)
    const unsigned long long* __restrict__ tabs,
    int A, int bpb) {
#pragma clang fp contract(off)
    __shared__ float4 sgt4[G];            // gt AoS: ONE b128 read per pair
    __shared__ unsigned long long tab[4][NSTRIP];                 // 4 KB
    __shared__ unsigned long long skey[G];                        // col keys
    __shared__ float sax0[ABLK], say0[ABLK], sax1[ABLK], say1[ABLK]; // 12 KB
    __shared__ unsigned short sidx[ABLK];                         // 1.5 KB
    __shared__ int hist[G];                                       // counts
    __shared__ int pfx[G];                                        // prefix/alloc

    const int b = blockIdx.x / bpb;
    const int t = threadIdx.x;
    const int base = (blockIdx.x % bpb) * ABLK;

    if (t < G) {
        sgt4[t] = gt[b * G + t];
        skey[t] = KEY_INIT;
        hist[t] = 0;
    }
    {   // 4 KB table: one ulonglong2 (16B) per thread
        const ulonglong2* src = (const ulonglong2*)(tabs + (size_t)b * 512);
        ((ulonglong2*)&tab[0][0])[t] = src[t];
    }

    // Prefetch this thread's anchors (global latency hides under staging).
    float4 anbuf[APT];
#pragma unroll
    for (int j = 0; j < APT; ++j)
        anbuf[j] = anchors[(size_t)b * A + base + j * BLOCK + t];

    __syncthreads();   // tab ready

    // ---- build: corners + popcount histogram (mask NOT stored: consume
    //      recomputes it from identical inputs -> identical bits) ----
    int pops[APT];
#pragma unroll
    for (int j = 0; j < APT; ++j) {
        const int k = j * BLOCK + t;
        const float4 an = anbuf[j];
        const float ax0 = an.x - 0.5f * an.z;
        const float ay0 = an.y - 0.5f * an.w;
        const float ax1 = an.x + 0.5f * an.z;
        const float ay1 = an.y + 0.5f * an.w;
        sax0[k] = ax0; say0[k] = ay0; sax1[k] = ax1; say1[k] = ay1;

        const unsigned long long mask =
            tab[0][stripclamp(ax1)] & tab[1][stripclamp(ax0)] &
            tab[2][stripclamp(ay1)] & tab[3][stripclamp(ay0)];
        pops[j] = __builtin_popcountll(mask);
        atomicAdd(&hist[pops[j] > 63 ? 63 : pops[j]], 1);
    }
    __syncthreads();

    // ---- one-wave exclusive scan of 64-bin histogram ----
    if (t < G) {
        const int c0 = hist[t];
        int x = c0;
#pragma unroll
        for (int d = 1; d < 64; d <<= 1) {
            int y = __shfl_up(x, d, 64);
            if (t >= d) x += y;
        }
        pfx[t] = x - c0;   // exclusive prefix
    }
    __syncthreads();

    // ---- slot allocation: sorted-by-popcount order ----
#pragma unroll
    for (int j = 0; j < APT; ++j) {
        const int bin = pops[j] > 63 ? 63 : pops[j];
        const int pos = atomicAdd(&pfx[bin], 1);
        sidx[pos] = (unsigned short)(j * BLOCK + t);
    }
    __syncthreads();

    // ---- consume: stratified sorted order; wave pops near-uniform ----
#pragma unroll
    for (int r = 0; r < APT; ++r) {
        const int k = (int)sidx[r * BLOCK + t];
        const int a = base + k;                      // within-batch anchor id
        const size_t idx = (size_t)b * A + a;
        const float ax0 = sax0[k], ay0 = say0[k];
        const float ax1 = sax1[k], ay1 = say1[k];
        const float area_a = (ax1 - ax0) * (ay1 - ay0);  // numpy corner-derived

        // recompute mask (bit-identical to build's: same corners, same tab)
        unsigned long long m =
            tab[0][stripclamp(ax1)] & tab[1][stripclamp(ax0)] &
            tab[2][stripclamp(ay1)] & tab[3][stripclamp(ay0)];

        float maxv = 0.0f;   // all-masked row => max_iou 0, argmax 0 (numpy)
        int maxg = 0;
        const unsigned long long inv_p =
            (unsigned long long)(0xFFFFFFFFu - (unsigned)a);

        // merged u64 loop, 2 pairs/iter, ascending g, odd tail duplicates the
        // last real bit (idempotent under strict > and same-key atomicMax).
        // Per pair: ONE ds_read_b128 + VALU area ((z-x)*(w-y), contract off:
        // numpy's exact area_g expression) + one atomicMax.
        while (m) {
            const int g1 = (int)__builtin_ctzll(m);          m &= m - 1;
            const int cand = (int)__builtin_ctzll(m | TOPBIT);
            const int g2 = m ? cand : g1;                    m &= m - 1;

            const float4 ga4 = sgt4[g1];
            const float4 gb4 = sgt4[g2];
            const float saa = (ga4.z - ga4.x) * (ga4.w - ga4.y);
            const float sab = (gb4.z - gb4.x) * (gb4.w - gb4.y);

            float lxa = fmaxf(ax0, ga4.x), lya = fmaxf(ay0, ga4.y);
            float rxa = fminf(ax1, ga4.z), rya = fminf(ay1, ga4.w);
            float wa = fmaxf(rxa - lxa, 0.0f), ha = fmaxf(rya - lya, 0.0f);
            float intera = wa * ha;
            float unia = area_a + saa - intera;
            float ioua = intera / unia;          // IEEE div: bit-exact vs numpy

            float lxb = fmaxf(ax0, gb4.x), lyb = fmaxf(ay0, gb4.y);
            float rxb = fminf(ax1, gb4.z), ryb = fminf(ay1, gb4.w);
            float wb = fmaxf(rxb - lxb, 0.0f), hb = fmaxf(ryb - lyb, 0.0f);
            float interb = wb * hb;
            float unib = area_a + sab - interb;
            float ioub = interb / unib;          // IEEE div: bit-exact vs numpy

            bool b1 = ioua > maxv; maxv = b1 ? ioua : maxv; maxg = b1 ? g1 : maxg;
            bool b2 = ioub > maxv; maxv = b2 ? ioub : maxv; maxg = b2 ? g2 : maxg;

            // iou==0 => key = inv_p <= KEY_INIT: atomicMax natural no-op.
            unsigned long long key1 =
                ((unsigned long long)__float_as_uint(ioua) << 32) | inv_p;
            unsigned long long key2 =
                ((unsigned long long)__float_as_uint(ioub) << 32) | inv_p;
            atomicMax(&skey[g1], key1);
            atomicMax(&skey[g2], key2);
        }

        const bool fg = maxv > FG_IOU;
        const bool bg = maxv < BG_IOU;
        const bool cross =
            (ax0 < 0.0f) || (ay0 < 0.0f) || (ax1 > IMG) || (ay1 > IMG);

        L[idx] = cross ? -1.0f : (fg ? 1.0f : (bg ? 0.0f : -1.0f));
        float4 mbox = make_float4(0.0f, 0.0f, 0.0f, 0.0f);
        if (fg)  // rare: usually whole-wave skipped; one b128 read
            mbox = sgt4[maxg];
        M[idx] = mbox;
        V[idx] = maxv;
    }

    __syncthreads();
    if (t < G) {
        // unconditional: every column must receive >= KEY_INIT (gkeys poisoned)
        atomicMax(&gkeys[b * G + t], (long long)skey[t]);
    }
}

// Rule 1 fixup: one block per batch, thread per gt. numpy scatter is
// last-write-wins; thread g writes only if no later g' targets the same anchor.
__global__ void fixup(
    const float4* __restrict__ anchors,
    const float4* __restrict__ gt,
    const long long* __restrict__ gkeys,
    float* __restrict__ L,
    float4* __restrict__ M,
    const float* __restrict__ V,
    int A) {
#pragma clang fp contract(off)
    const int b = blockIdx.x;
    const int g = threadIdx.x;
    __shared__ int tgt[G];

    unsigned long long key = (unsigned long long)gkeys[b * G + g];
    unsigned int a = 0xFFFFFFFFu - (unsigned int)(key & 0xFFFFFFFFull);
    tgt[g] = (int)a;
    __syncthreads();

    bool write = true;
    for (int g2 = g + 1; g2 < G; ++g2)
        if (tgt[g2] == (int)a) { write = false; break; }
    if (!write) return;

    const size_t idx = (size_t)b * A + a;
    float4 an = anchors[idx];
    float ax0 = an.x - 0.5f * an.z;
    float ay0 = an.y - 0.5f * an.w;
    float ax1 = an.x + 0.5f * an.z;
    float ay1 = an.y + 0.5f * an.w;
    bool cross = (ax0 < 0.0f) || (ay0 < 0.0f) || (ax1 > IMG) || (ay1 > IMG);
    // Rule 1 label=1 overrides rule-3 bg; cross filter still wins.
    L[idx] = cross ? -1.0f : 1.0f;
    // Rule 2 (fg) overrides rule 1's matched box; otherwise rule 1 assigns gt[g].
    if (!(V[idx] > FG_IOU)) M[idx] = gt[b * G + g];
}

extern "C" void kernel_launch(void* const* d_in, const int* in_sizes, int n_in,
                              void* d_out, int out_size, void* d_ws, size_t ws_size,
                              hipStream_t stream) {
    const float4* anchors = (const float4*)d_in[0];
    const float4* gt      = (const float4*)d_in[1];
    const int A = in_sizes[0] / (B * 4);

    float* out = (float*)d_out;
    float*  L = out;                                 // [B*A]
    float4* M = (float4*)(out + (size_t)B * A);      // [B*A] float4
    float*  V = out + (size_t)B * A * 5;             // [B*A]

    char* ws = (char*)d_ws;
    long long* gkeys = (long long*)(ws + 256);       // poison 0xAA.. == -inf (i64)
    unsigned long long* tabs = (unsigned long long*)(ws + 8192);  // B*4*128 u64

    const int bpb = A / ABLK;                        // 184320/768 = 240
    build_tables<<<B, 512, 0, stream>>>(gt, tabs);
    assign_main<<<B * bpb, BLOCK, 0, stream>>>(anchors, gt, L, M, V, gkeys,
                                               tabs, A, bpb);
    fixup<<<B, G, 0, stream>>>(anchors, gt, gkeys, L, M, V, A);
}